// Round 15
// baseline (161.891 us; speedup 1.0000x reference)
//
#include <hip/hip_runtime.h>
#include <hip/hip_bf16.h>

typedef __attribute__((ext_vector_type(8))) short bf16x8;
typedef __attribute__((ext_vector_type(4))) float f32x4;
typedef __attribute__((ext_vector_type(4))) unsigned int u32x4;
typedef __attribute__((ext_vector_type(2))) unsigned int u32x2;
typedef __attribute__((ext_vector_type(2))) __bf16 bf16x2v;

#define EPS 1e-5f

__device__ inline unsigned short f2bf(float x) {  // RNE (prep kernel only; cold)
  unsigned int u = __builtin_bit_cast(unsigned int, x);
  unsigned int r = (u + 0x7FFFu + ((u >> 16) & 1u)) >> 16;
  return (unsigned short)r;
}

// pair pack: compiles to v_cvt_pk_bf16_f32 (1 VALU op; RNE)
__device__ inline unsigned int cvtpk(float a, float b) {
  bf16x2v v = {(__bf16)a, (__bf16)b};
  return __builtin_bit_cast(unsigned int, v);
}

#define MFMA16(A, B, C) __builtin_amdgcn_mfma_f32_16x16x32_bf16((A), (B), (C), 0, 0, 0)

// ---------------- prep: fold BN, pre-swizzle W1/W2 into MFMA fragment order ----------------
// ws layout: w1f bf16 [73728 B] | w2f bf16 [16384 B] | sc f32[384]
// W2 rows permuted: physical k-slot s holds logical row (s&96)|((s&1)<<4)|((s>>1)&15)
// — matches the packed x1 writes.
__global__ void prep_kernel(const float* __restrict__ W1, const float* __restrict__ W2,
                            const float* __restrict__ b1, const float* __restrict__ g1,
                            const float* __restrict__ be1, const float* __restrict__ m1,
                            const float* __restrict__ v1,
                            const float* __restrict__ b2, const float* __restrict__ g2,
                            const float* __restrict__ be2, const float* __restrict__ m2,
                            const float* __restrict__ v2,
                            unsigned short* __restrict__ w1f, unsigned short* __restrict__ w2f,
                            float* __restrict__ sc) {
  int t = blockIdx.x * 256 + threadIdx.x;
  if (t < 36864) {
    int j = t & 7, l = (t >> 3) & 63, f = t >> 9;
    int kb = f >> 3, nb = f & 7;
    int rk = kb * 32 + ((l >> 4) << 3) + j;
    int cn = (nb << 4) + (l & 15);
    w1f[t] = f2bf(W1[rk * 128 + cn]);
  } else if (t < 45056) {
    int o = t - 36864;
    int j = o & 7, l = (o >> 3) & 63, f = o >> 9;
    int kb = f >> 2, nb = f & 3;
    int s = kb * 32 + ((l >> 4) << 3) + j;                 // physical k-slot
    int rk = (s & 96) | ((s & 1) << 4) | ((s >> 1) & 15);  // logical W2 row
    int cn = (nb << 4) + (l & 15);
    w2f[o] = f2bf(W2[rk * 64 + cn]);
  } else if (t < 45184) {
    int j = t - 45056;
    float s = g1[j] * rsqrtf(v1[j] + EPS);
    sc[j] = s;
    sc[128 + j] = (b1[j] - m1[j]) * s + be1[j];
  } else if (t < 45248) {
    int j = t - 45184;
    float s = g2[j] * rsqrtf(v2[j] + EPS);
    sc[256 + j] = s;
    sc[320 + j] = (b2[j] - m2[j]) * s + be2[j];
  }
}

// ================= PRIMARY q: 64-edge tiles, 1024 thr / 16 waves, TWO barriers =================
// x1 has its OWN region (no A-alias) -> A-write(t+1) merges with L2/l3/gathers into one
// mixed phase. Loop: P1{L1+x1w} B1 P2{A-w(t+1) | gathers(t+2) | L2 | l3} B2 P3{out}.
// Cost: thin wave tiles (16x32) -> L1 traffic 6.75 KB/edge vs f's 4.5. Tests barrier-overlap
// vs LDS-BW directly.
// LDS: [0,73728) W1 | [73728,114688) A [64 x 640B] | [114688,131072) x1 [64 x 256B] |
//      [131072,132096) l3 f32[64][4]
#define Q_A_OFF 73728
#define Q_X1_OFF 114688
#define Q_L3_OFF 131072
#define Q_LDS_TOTAL 132096

// staging: 16 threads/edge (sr=tid>>4 in [0,64), h=tid&15)
#define GATHER_Q(tg)                                                                             \
  do {                                                                                           \
    sv = *(const f32x4*)(z + ((size_t)iN0 * 64 + h * 4));                                        \
    dv = *(const f32x4*)(z + ((size_t)iN1 * 64 + h * 4));                                        \
    int eg_ = (tg) * 64 + sr;                                                                    \
    int esg_ = eg_ < E ? eg_ : E - 1;                                                            \
    if (h < 8) cv = *(const f32x4*)(ctx + (size_t)esg_ * 32 + h * 4);                            \
    int tn_ = (tg) + grid;                                                                       \
    if (tn_ >= nblk) tn_ = (tg);                                                                 \
    int en_ = tn_ * 64 + sr;                                                                     \
    int esn_ = en_ < E ? en_ : E - 1;                                                            \
    iN0 = ei[esn_];                                                                              \
    iN1 = ei[E + esn_];                                                                          \
  } while (0)

#define WRITE_A_Q()                                                                              \
  do {                                                                                           \
    const int rswz_ = (sr & 7) << 4;                                                             \
    char* rowp_ = AQ + sr * 640;                                                                 \
    u32x2 s_ = {cvtpk(sv[0], sv[1]), cvtpk(sv[2], sv[3])};                                       \
    u32x2 d_ = {cvtpk(dv[0], dv[1]), cvtpk(dv[2], dv[3])};                                       \
    u32x2 p_ = {cvtpk(sv[0] * dv[0], sv[1] * dv[1]), cvtpk(sv[2] * dv[2], sv[3] * dv[3])};       \
    u32x2 a_ = {cvtpk(fabsf(sv[0] - dv[0]), fabsf(sv[1] - dv[1])),                               \
                cvtpk(fabsf(sv[2] - dv[2]), fabsf(sv[3] - dv[3]))};                              \
    *(u32x2*)(rowp_ + ((h * 8) ^ rswz_)) = s_;                                                   \
    *(u32x2*)(rowp_ + ((128 + h * 8) ^ rswz_)) = d_;                                             \
    *(u32x2*)(rowp_ + ((256 + h * 8) ^ rswz_)) = p_;                                             \
    *(u32x2*)(rowp_ + ((384 + h * 8) ^ rswz_)) = a_;                                             \
    if (h < 8) {                                                                                 \
      u32x2 c_ = {cvtpk(cv[0], cv[1]), cvtpk(cv[2], cv[3])};                                     \
      *(u32x2*)(rowp_ + 512 + ((h * 8) ^ rswz_)) = c_;                                           \
    }                                                                                            \
  } while (0)

__global__ __launch_bounds__(1024) void fused_kernel_q(
    const float* __restrict__ z, const int* __restrict__ ei, const float* __restrict__ ctx,
    const unsigned short* __restrict__ w1f, const unsigned short* __restrict__ w2f,
    const float* __restrict__ sc, const float* __restrict__ w3, const float* __restrict__ b3,
    float* __restrict__ out, int E, int nblk) {
  extern __shared__ char lds[];
  char* W1L = lds;
  char* AQ = lds + Q_A_OFF;
  char* X1 = lds + Q_X1_OFF;
  float* l3 = (float*)(lds + Q_L3_OFF);

  const int tid = threadIdx.x;
  const int lane = tid & 63, wave = tid >> 6;  // 16 waves
  const int g = lane >> 4, lq = lane & 15;
  const int mb = wave >> 2, ng = wave & 3;     // L1: 4 row-blocks(16) x 4 col-groups(32)
  const int m2 = wave >> 2, n2 = wave & 3;     // L2: 4 row-blocks(16) x 4 col-frags(16)
  const int sr = tid >> 4, h = tid & 15;       // staging: 16 threads/edge
  const int grid = gridDim.x;

  // ---- stage W1 (72 KB) into LDS ----
  {
    const f32x4* s = (const f32x4*)w1f;
    f32x4* d = (f32x4*)W1L;
#pragma unroll
    for (int i = 0; i < 4; i++) d[i * 1024 + tid] = s[i * 1024 + tid];
    if (tid < 512) d[4096 + tid] = s[4096 + tid];
  }

  // ---- hoisted constants (regs) ----
  const float s1v0 = sc[ng * 32 + lq], c1v0 = sc[128 + ng * 32 + lq];
  const float s1v1 = sc[ng * 32 + 16 + lq], c1v1 = sc[128 + ng * 32 + 16 + lq];
  const int colq = n2 * 16 + lq;
  const float s2v = sc[256 + colq], c2v = sc[320 + colq], w3v = w3[colq];
  const float b3v = b3[0];
  const int xoff = ng * 64 + lq * 4;

  // ---- W2 fragments in regs: 4 kb x 1 n-frag (n2) = 16 VGPR ----
  const bf16x8* W2G = (const bf16x8*)w2f;
  bf16x8 w2q0 = W2G[(0 * 4 + n2) * 64 + lane];
  bf16x8 w2q1 = W2G[(1 * 4 + n2) * 64 + lane];
  bf16x8 w2q2 = W2G[(2 * 4 + n2) * 64 + lane];
  bf16x8 w2q3 = W2G[(3 * 4 + n2) * 64 + lane];

  f32x4 sv, dv, cv;
  int iN0, iN1;
  int t = blockIdx.x;

  // ---- prologue: i(t); gather(t); A-write(t); gather(t+1); barrier ----
  {
    int e = t * 64 + sr;
    int es = e < E ? e : E - 1;
    iN0 = ei[es];
    iN1 = ei[E + es];
  }
  GATHER_Q(t);
  WRITE_A_Q();
  {
    int tn = t + grid;
    if (tn >= nblk) tn = t;
    GATHER_Q(tn);
  }
  __syncthreads();  // A(t) + W1L visible

  const bf16x8* W1F = (const bf16x8*)W1L;
  const int arow = mb * 16 + lq;
  const char* apq = AQ + arow * 640;
  const int aswz = (arow & 7) << 4;
  const int xrow = m2 * 16 + lq;
  const char* xpq = X1 + xrow * 256;
  const int xswz = (xrow & 7) << 4;

  for (; t < nblk; t += grid) {
    // ---- P1: L1 (A[64x288] @ W1; wave 16x32 = 1m x 2n frags) + x1-write (own acc) ----
    f32x4 acc0 = {0.f, 0.f, 0.f, 0.f}, acc1 = acc0;
#pragma unroll
    for (int kb = 0; kb < 9; kb++) {
      bf16x8 a = *(const bf16x8*)(apq + ((kb * 64 + g * 16) ^ aswz));
      bf16x8 b0 = W1F[(kb * 8 + ng * 2 + 0) * 64 + lane];
      bf16x8 b1 = W1F[(kb * 8 + ng * 2 + 1) * 64 + lane];
      acc0 = MFMA16(a, b0, acc0);
      acc1 = MFMA16(a, b1, acc1);
    }
#pragma unroll
    for (int j = 0; j < 4; j++) {
      int row = mb * 16 + 4 * g + j;
      unsigned int pk = cvtpk(fmaxf(acc0[j] * s1v0 + c1v0, 0.f),
                              fmaxf(acc1[j] * s1v1 + c1v1, 0.f));
      *(unsigned int*)(X1 + row * 256 + (xoff ^ ((row & 7) << 4))) = pk;
    }
    __syncthreads();  // B1: x1(t) visible; all A(t) reads done

    // ---- P2: A-write(t+1) | gathers(t+2) | L2 | l3 — mixed-pipe phase ----
    WRITE_A_Q();  // consumes t+1 regs (A unaliased: only needs B1)
    {
      int tn2 = t + 2 * grid;
      if (tn2 >= nblk) tn2 = t + grid < nblk ? t + grid : t;
      GATHER_Q(tn2);  // long-latency; consumed next P2
    }
    f32x4 acc2 = {0.f, 0.f, 0.f, 0.f};
    {
      bf16x8 a0 = *(const bf16x8*)(xpq + ((0 * 64 + g * 16) ^ xswz));
      acc2 = MFMA16(a0, w2q0, acc2);
      bf16x8 a1 = *(const bf16x8*)(xpq + ((1 * 64 + g * 16) ^ xswz));
      acc2 = MFMA16(a1, w2q1, acc2);
      bf16x8 a2 = *(const bf16x8*)(xpq + ((2 * 64 + g * 16) ^ xswz));
      acc2 = MFMA16(a2, w2q2, acc2);
      bf16x8 a3 = *(const bf16x8*)(xpq + ((3 * 64 + g * 16) ^ xswz));
      acc2 = MFMA16(a3, w2q3, acc2);
    }
#pragma unroll
    for (int j = 0; j < 4; j++) {
      float p = fmaxf(acc2[j] * s2v + c2v, 0.f) * w3v;
      p += __shfl_xor(p, 1);
      p += __shfl_xor(p, 2);
      p += __shfl_xor(p, 4);
      p += __shfl_xor(p, 8);
      if (lq == 0) l3[(m2 * 16 + 4 * g + j) * 4 + n2] = p;
    }
    __syncthreads();  // B2: l3 + A(t+1) visible; x1(t) reads done

    // ---- P3: out(t) (no barrier; next l3 write is after B1') ----
    if (tid < 64) {
      int e = t * 64 + tid;
      if (e < E) {
        f32x4 lv = *(const f32x4*)(l3 + tid * 4);
        out[e] = lv[0] + lv[1] + lv[2] + lv[3] + b3v;
      }
    }
  }
}

// ================= FALLBACK f: proven 137-us kernel =================
#define F_SC_OFF 73728
#define F_A_OFF 75776
#define F_L3_OFF 157696
#define F_LDS_TOTAL 158720

typedef __attribute__((ext_vector_type(4))) float f32x4_;

#define WRITE_A_F()                                                                              \
  do {                                                                                           \
    const int rswz_ = (sr & 7) << 4;                                                             \
    char* rowp_ = AR + sr * 640;                                                                 \
    u32x4 ps_ = {cvtpk(sv0[0], sv0[1]), cvtpk(sv0[2], sv0[3]), cvtpk(sv1[0], sv1[1]),            \
                 cvtpk(sv1[2], sv1[3])};                                                         \
    u32x4 pd_ = {cvtpk(dv0[0], dv0[1]), cvtpk(dv0[2], dv0[3]), cvtpk(dv1[0], dv1[1]),            \
                 cvtpk(dv1[2], dv1[3])};                                                         \
    u32x4 pp_ = {cvtpk(sv0[0] * dv0[0], sv0[1] * dv0[1]), cvtpk(sv0[2] * dv0[2], sv0[3] * dv0[3]),\
                 cvtpk(sv1[0] * dv1[0], sv1[1] * dv1[1]), cvtpk(sv1[2] * dv1[2], sv1[3] * dv1[3])};\
    u32x4 pa_ = {cvtpk(fabsf(sv0[0] - dv0[0]), fabsf(sv0[1] - dv0[1])),                          \
                 cvtpk(fabsf(sv0[2] - dv0[2]), fabsf(sv0[3] - dv0[3])),                          \
                 cvtpk(fabsf(sv1[0] - dv1[0]), fabsf(sv1[1] - dv1[1])),                          \
                 cvtpk(fabsf(sv1[2] - dv1[2]), fabsf(sv1[3] - dv1[3]))};                         \
    u32x2 pc_ = {cvtpk(cv[0], cv[1]), cvtpk(cv[2], cv[3])};                                      \
    *(u32x4*)(rowp_ + ((sh * 16) ^ rswz_)) = ps_;                                                \
    *(u32x4*)(rowp_ + ((128 + sh * 16) ^ rswz_)) = pd_;                                          \
    *(u32x4*)(rowp_ + ((256 + sh * 16) ^ rswz_)) = pp_;                                          \
    *(u32x4*)(rowp_ + ((384 + sh * 16) ^ rswz_)) = pa_;                                          \
    *(u32x2*)(rowp_ + 512 + ((sh * 8) ^ rswz_)) = pc_;                                           \
  } while (0)

#define GATHER_NEXT_F(tg)                                                                        \
  do {                                                                                           \
    const f32x4* zs_ = (const f32x4*)(z + ((size_t)i0n * 64 + sh * 8));                          \
    sv0 = zs_[0];                                                                                \
    sv1 = zs_[1];                                                                                \
    const f32x4* zd_ = (const f32x4*)(z + ((size_t)i1n * 64 + sh * 8));                          \
    dv0 = zd_[0];                                                                                \
    dv1 = zd_[1];                                                                                \
    int eg_ = ((tg) << 7) + sr;                                                                  \
    int esg_ = eg_ < E ? eg_ : E - 1;                                                            \
    cv = *(const f32x4*)(ctx + (size_t)esg_ * 32 + sh * 4);                                      \
    int tn_ = (tg) + grid;                                                                       \
    if (tn_ >= nblk) tn_ = (tg);                                                                 \
    int en_ = (tn_ << 7) + sr;                                                                   \
    int esn_ = en_ < E ? en_ : E - 1;                                                            \
    i0n = ei[esn_];                                                                              \
    i1n = ei[E + esn_];                                                                          \
  } while (0)

__global__ __launch_bounds__(1024, 4) void fused_kernel_f(
    const float* __restrict__ z, const int* __restrict__ ei, const float* __restrict__ ctx,
    const unsigned short* __restrict__ w1f, const unsigned short* __restrict__ w2f,
    const float* __restrict__ sc, const float* __restrict__ w3, const float* __restrict__ b3,
    float* __restrict__ out, int E, int nblk) {
  extern __shared__ char lds[];
  char* W1L = lds;
  float* SC = (float*)(lds + F_SC_OFF);
  char* AR = lds + F_A_OFF;
  char* X1 = lds + F_A_OFF;
  float* l3 = (float*)(lds + F_L3_OFF);

  const int tid = threadIdx.x;
  const int lane = tid & 63, wave = tid >> 6;
  const int g = lane >> 4, lq = lane & 15;
  const int wr = wave >> 2, wc = wave & 3;
  const int w2r = wave >> 1, w2c = wave & 1;
  const int sr = tid >> 3, sh = tid & 7;
  const int grid = gridDim.x;

  {
    const f32x4* s = (const f32x4*)w1f;
    f32x4* d = (f32x4*)W1L;
#pragma unroll
    for (int i = 0; i < 4; i++) d[i * 1024 + tid] = s[i * 1024 + tid];
    if (tid < 512) d[4096 + tid] = s[4096 + tid];
    if (tid < 128) {
      SC[tid] = sc[tid];
      SC[128 + tid] = sc[128 + tid];
    } else if (tid < 192) {
      int j = tid - 128;
      SC[256 + j] = sc[256 + j];
      SC[320 + j] = sc[320 + j];
      SC[384 + j] = w3[j];
    } else if (tid == 192) {
      SC[448] = b3[0];
    }
  }

  bf16x8 w2g0, w2g1, w2g2, w2g3, w2h0, w2h1, w2h2, w2h3;
  {
    const bf16x8* W2G = (const bf16x8*)w2f;
    w2g0 = W2G[(0 * 4 + w2c * 2 + 0) * 64 + lane];
    w2h0 = W2G[(0 * 4 + w2c * 2 + 1) * 64 + lane];
    w2g1 = W2G[(1 * 4 + w2c * 2 + 0) * 64 + lane];
    w2h1 = W2G[(1 * 4 + w2c * 2 + 1) * 64 + lane];
    w2g2 = W2G[(2 * 4 + w2c * 2 + 0) * 64 + lane];
    w2h2 = W2G[(2 * 4 + w2c * 2 + 1) * 64 + lane];
    w2g3 = W2G[(3 * 4 + w2c * 2 + 0) * 64 + lane];
    w2h3 = W2G[(3 * 4 + w2c * 2 + 1) * 64 + lane];
  }

  f32x4 sv0, sv1, dv0, dv1, cv;
  int i0n, i1n;
  int t = blockIdx.x;

  {
    int e = (t << 7) + sr;
    int es = e < E ? e : E - 1;
    int a0 = ei[es], a1 = ei[E + es];
    cv = *(const f32x4*)(ctx + (size_t)es * 32 + sh * 4);
    const f32x4* zs = (const f32x4*)(z + ((size_t)a0 * 64 + sh * 8));
    sv0 = zs[0];
    sv1 = zs[1];
    const f32x4* zd = (const f32x4*)(z + ((size_t)a1 * 64 + sh * 8));
    dv0 = zd[0];
    dv1 = zd[1];
    int tn = t + grid;
    if (tn >= nblk) tn = t;
    int en = (tn << 7) + sr;
    int esn = en < E ? en : E - 1;
    i0n = ei[esn];
    i1n = ei[E + esn];
  }
  WRITE_A_F();
  {
    int tn = t + grid;
    if (tn >= nblk) tn = t;
    GATHER_NEXT_F(tn);
  }
  __syncthreads();

  for (; t < nblk; t += grid) {
    f32x4 acc00 = {0.f, 0.f, 0.f, 0.f}, acc01 = acc00, acc10 = acc00, acc11 = acc00;
    const bf16x8* W1F = (const bf16x8*)W1L;
    const int row0 = wr * 32 + lq, row1 = row0 + 16;
    const int swz0 = (row0 & 7) << 4, swz1 = (row1 & 7) << 4;
    const char* ap0 = AR + row0 * 640;
    const char* ap1 = AR + row1 * 640;
#pragma unroll
    for (int kb = 0; kb < 9; kb++) {
      bf16x8 a0 = *(const bf16x8*)(ap0 + ((kb * 64 + g * 16) ^ swz0));
      bf16x8 a1 = *(const bf16x8*)(ap1 + ((kb * 64 + g * 16) ^ swz1));
      bf16x8 b0 = W1F[(kb * 8 + wc * 2 + 0) * 64 + lane];
      bf16x8 b1 = W1F[(kb * 8 + wc * 2 + 1) * 64 + lane];
      acc00 = MFMA16(a0, b0, acc00);
      acc01 = MFMA16(a0, b1, acc01);
      acc10 = MFMA16(a1, b0, acc10);
      acc11 = MFMA16(a1, b1, acc11);
    }
    __syncthreads();

    {
      const int col0 = wc * 32 + lq;
      const float s1v0 = SC[col0], c1v0 = SC[128 + col0];
      const float s1v1 = SC[col0 + 16], c1v1 = SC[128 + col0 + 16];
      const int xoff = wc * 64 + lq * 4;
#pragma unroll
      for (int j = 0; j < 4; j++) {
        int rowa = wr * 32 + 4 * g + j;
        unsigned int pA = cvtpk(fmaxf(acc00[j] * s1v0 + c1v0, 0.f),
                                fmaxf(acc01[j] * s1v1 + c1v1, 0.f));
        *(unsigned int*)(X1 + rowa * 256 + (xoff ^ ((rowa & 7) << 4))) = pA;
        int rowb = rowa + 16;
        unsigned int pB = cvtpk(fmaxf(acc10[j] * s1v0 + c1v0, 0.f),
                                fmaxf(acc11[j] * s1v1 + c1v1, 0.f));
        *(unsigned int*)(X1 + rowb * 256 + (xoff ^ ((rowb & 7) << 4))) = pB;
      }
    }
    __syncthreads();

    f32x4 acc2A = {0.f, 0.f, 0.f, 0.f}, acc2B = acc2A;
    {
      const int row = w2r * 16 + lq;
      const int swz = (row & 7) << 4;
      const char* xp = X1 + row * 256;
      bf16x8 a0 = *(const bf16x8*)(xp + ((0 * 64 + g * 16) ^ swz));
      acc2A = MFMA16(a0, w2g0, acc2A);
      acc2B = MFMA16(a0, w2h0, acc2B);
      bf16x8 a1 = *(const bf16x8*)(xp + ((1 * 64 + g * 16) ^ swz));
      acc2A = MFMA16(a1, w2g1, acc2A);
      acc2B = MFMA16(a1, w2h1, acc2B);
      bf16x8 a2 = *(const bf16x8*)(xp + ((2 * 64 + g * 16) ^ swz));
      acc2A = MFMA16(a2, w2g2, acc2A);
      acc2B = MFMA16(a2, w2h2, acc2B);
      bf16x8 a3 = *(const bf16x8*)(xp + ((3 * 64 + g * 16) ^ swz));
      acc2A = MFMA16(a3, w2g3, acc2A);
      acc2B = MFMA16(a3, w2h3, acc2B);
    }

    const int colA = w2c * 32 + lq, colB = colA + 16;
    const float s2A = SC[256 + colA], c2A = SC[320 + colA];
    const float s2B = SC[256 + colB], c2B = SC[320 + colB];
    const float w3A = SC[384 + colA], w3B = SC[384 + colB];
#pragma unroll
    for (int j = 0; j < 4; j++) {
      float vA = fmaxf(acc2A[j] * s2A + c2A, 0.f);
      float vB = fmaxf(acc2B[j] * s2B + c2B, 0.f);
      float p = vA * w3A + vB * w3B;
      p += __shfl_xor(p, 1);
      p += __shfl_xor(p, 2);
      p += __shfl_xor(p, 4);
      p += __shfl_xor(p, 8);
      if (lq == 0) l3[(w2r * 16 + 4 * g + j) * 2 + w2c] = p;
    }
    __syncthreads();

    WRITE_A_F();
    {
      int tn2 = t + 2 * grid;
      if (tn2 >= nblk) tn2 = t + grid < nblk ? t + grid : t;
      GATHER_NEXT_F(tn2);
    }
    if (tid < 128) {
      int e = (t << 7) + tid;
      if (e < E) out[e] = l3[tid * 2] + l3[tid * 2 + 1] + SC[448];
    }
    __syncthreads();
  }
}

extern "C" void kernel_launch(void* const* d_in, const int* in_sizes, int n_in,
                              void* d_out, int out_size, void* d_ws, size_t ws_size,
                              hipStream_t stream) {
  const float* z = (const float*)d_in[0];
  const int* ei = (const int*)d_in[1];
  const float* ctx = (const float*)d_in[2];
  const float* W1 = (const float*)d_in[3];
  const float* b1 = (const float*)d_in[4];
  const float* g1 = (const float*)d_in[5];
  const float* be1 = (const float*)d_in[6];
  const float* m1 = (const float*)d_in[7];
  const float* v1 = (const float*)d_in[8];
  const float* W2 = (const float*)d_in[9];
  const float* b2 = (const float*)d_in[10];
  const float* g2 = (const float*)d_in[11];
  const float* be2 = (const float*)d_in[12];
  const float* m2 = (const float*)d_in[13];
  const float* v2 = (const float*)d_in[14];
  const float* W3 = (const float*)d_in[15];
  const float* b3 = (const float*)d_in[16];
  float* out = (float*)d_out;
  const int E = out_size;

  unsigned short* w1f = (unsigned short*)d_ws;
  unsigned short* w2f = (unsigned short*)((char*)d_ws + 73728);
  float* sc = (float*)((char*)d_ws + 90112);

  prep_kernel<<<177, 256, 0, stream>>>(W1, W2, b1, g1, be1, m1, v1,
                                       b2, g2, be2, m2, v2, w1f, w2f, sc);

  // Primary only if spill-free (localSizeBytes == 0); else proven fallback.
  hipFuncAttributes attr;
  bool use_q = false;
  if (hipFuncGetAttributes(&attr, (const void*)fused_kernel_q) == hipSuccess) {
    use_q = (attr.localSizeBytes < 16);
  }

  if (use_q) {
    const int nblk = (E + 63) >> 6;
    (void)hipFuncSetAttribute((const void*)fused_kernel_q,
                              hipFuncAttributeMaxDynamicSharedMemorySize, Q_LDS_TOTAL);
    fused_kernel_q<<<256, 1024, Q_LDS_TOTAL, stream>>>(z, ei, ctx, w1f, w2f, sc, W3, b3,
                                                       out, E, nblk);
  } else {
    const int nblk = (E + 127) >> 7;
    (void)hipFuncSetAttribute((const void*)fused_kernel_f,
                              hipFuncAttributeMaxDynamicSharedMemorySize, F_LDS_TOTAL);
    fused_kernel_f<<<256, 1024, F_LDS_TOTAL, stream>>>(z, ei, ctx, w1f, w2f, sc, W3, b3,
                                                       out, E, nblk);
  }
}

// Round 16
// 137.123 us; speedup vs baseline: 1.1806x; 1.1806x over previous
//
#include <hip/hip_runtime.h>
#include <hip/hip_bf16.h>

typedef __attribute__((ext_vector_type(8))) short bf16x8;
typedef __attribute__((ext_vector_type(4))) float f32x4;
typedef __attribute__((ext_vector_type(4))) unsigned int u32x4;
typedef __attribute__((ext_vector_type(2))) unsigned int u32x2;
typedef __attribute__((ext_vector_type(2))) __bf16 bf16x2v;

#define EPS 1e-5f

__device__ inline unsigned short f2bf(float x) {  // RNE (prep kernel only; cold)
  unsigned int u = __builtin_bit_cast(unsigned int, x);
  unsigned int r = (u + 0x7FFFu + ((u >> 16) & 1u)) >> 16;
  return (unsigned short)r;
}

// pair pack: compiles to v_cvt_pk_bf16_f32 (1 VALU op; RNE)
__device__ inline unsigned int cvtpk(float a, float b) {
  bf16x2v v = {(__bf16)a, (__bf16)b};
  return __builtin_bit_cast(unsigned int, v);
}

#define MFMA16(A, B, C) __builtin_amdgcn_mfma_f32_16x16x32_bf16((A), (B), (C), 0, 0, 0)

// ---------------- prep: fold BN, pre-swizzle W1/W2 into MFMA fragment order ----------------
// ws layout: w1f bf16 [73728 B] | w2f bf16 [16384 B] | sc f32[384]
// W2 rows permuted: physical k-slot s holds logical row (s&96)|((s&1)<<4)|((s>>1)&15)
// — matches the packed x1 writes.
__global__ void prep_kernel(const float* __restrict__ W1, const float* __restrict__ W2,
                            const float* __restrict__ b1, const float* __restrict__ g1,
                            const float* __restrict__ be1, const float* __restrict__ m1,
                            const float* __restrict__ v1,
                            const float* __restrict__ b2, const float* __restrict__ g2,
                            const float* __restrict__ be2, const float* __restrict__ m2,
                            const float* __restrict__ v2,
                            unsigned short* __restrict__ w1f, unsigned short* __restrict__ w2f,
                            float* __restrict__ sc) {
  int t = blockIdx.x * 256 + threadIdx.x;
  if (t < 36864) {
    int j = t & 7, l = (t >> 3) & 63, f = t >> 9;
    int kb = f >> 3, nb = f & 7;
    int rk = kb * 32 + ((l >> 4) << 3) + j;
    int cn = (nb << 4) + (l & 15);
    w1f[t] = f2bf(W1[rk * 128 + cn]);
  } else if (t < 45056) {
    int o = t - 36864;
    int j = o & 7, l = (o >> 3) & 63, f = o >> 9;
    int kb = f >> 2, nb = f & 3;
    int s = kb * 32 + ((l >> 4) << 3) + j;                 // physical k-slot
    int rk = (s & 96) | ((s & 1) << 4) | ((s >> 1) & 15);  // logical W2 row
    int cn = (nb << 4) + (l & 15);
    w2f[o] = f2bf(W2[rk * 64 + cn]);
  } else if (t < 45184) {
    int j = t - 45056;
    float s = g1[j] * rsqrtf(v1[j] + EPS);
    sc[j] = s;
    sc[128 + j] = (b1[j] - m1[j]) * s + be1[j];
  } else if (t < 45248) {
    int j = t - 45184;
    float s = g2[j] * rsqrtf(v2[j] + EPS);
    sc[256 + j] = s;
    sc[320 + j] = (b2[j] - m2[j]) * s + be2[j];
  }
}

// ================= fused kernel f: best-measured configuration (137.2 us) =================
// 1024 thr / 16 waves; 128-edge tiles; 4x4 L1 wave grid (operand-traffic optimum);
// W1 in LDS (regs spill at the 128-reg toolchain clamp [R7-11]; global thrashes L2 [R13]);
// W2 in regs; x1 aliases A-head; 4 barriers/iter; gathers issued 2 tiles ahead.
// LDS-pipe duty ~82% of b128 ceiling incl. barrier drains — structural limit of this form.
#define F_SC_OFF 73728
#define F_A_OFF 75776
#define F_L3_OFF 157696
#define F_LDS_TOTAL 158720

#define WRITE_A_F()                                                                              \
  do {                                                                                           \
    const int rswz_ = (sr & 7) << 4;                                                             \
    char* rowp_ = AR + sr * 640;                                                                 \
    u32x4 ps_ = {cvtpk(sv0[0], sv0[1]), cvtpk(sv0[2], sv0[3]), cvtpk(sv1[0], sv1[1]),            \
                 cvtpk(sv1[2], sv1[3])};                                                         \
    u32x4 pd_ = {cvtpk(dv0[0], dv0[1]), cvtpk(dv0[2], dv0[3]), cvtpk(dv1[0], dv1[1]),            \
                 cvtpk(dv1[2], dv1[3])};                                                         \
    u32x4 pp_ = {cvtpk(sv0[0] * dv0[0], sv0[1] * dv0[1]), cvtpk(sv0[2] * dv0[2], sv0[3] * dv0[3]),\
                 cvtpk(sv1[0] * dv1[0], sv1[1] * dv1[1]), cvtpk(sv1[2] * dv1[2], sv1[3] * dv1[3])};\
    u32x4 pa_ = {cvtpk(fabsf(sv0[0] - dv0[0]), fabsf(sv0[1] - dv0[1])),                          \
                 cvtpk(fabsf(sv0[2] - dv0[2]), fabsf(sv0[3] - dv0[3])),                          \
                 cvtpk(fabsf(sv1[0] - dv1[0]), fabsf(sv1[1] - dv1[1])),                          \
                 cvtpk(fabsf(sv1[2] - dv1[2]), fabsf(sv1[3] - dv1[3]))};                         \
    u32x2 pc_ = {cvtpk(cv[0], cv[1]), cvtpk(cv[2], cv[3])};                                      \
    *(u32x4*)(rowp_ + ((sh * 16) ^ rswz_)) = ps_;                                                \
    *(u32x4*)(rowp_ + ((128 + sh * 16) ^ rswz_)) = pd_;                                          \
    *(u32x4*)(rowp_ + ((256 + sh * 16) ^ rswz_)) = pp_;                                          \
    *(u32x4*)(rowp_ + ((384 + sh * 16) ^ rswz_)) = pa_;                                          \
    *(u32x2*)(rowp_ + 512 + ((sh * 8) ^ rswz_)) = pc_;                                           \
  } while (0)

#define GATHER_NEXT_F(tg)                                                                        \
  do {                                                                                           \
    const f32x4* zs_ = (const f32x4*)(z + ((size_t)i0n * 64 + sh * 8));                          \
    sv0 = zs_[0];                                                                                \
    sv1 = zs_[1];                                                                                \
    const f32x4* zd_ = (const f32x4*)(z + ((size_t)i1n * 64 + sh * 8));                          \
    dv0 = zd_[0];                                                                                \
    dv1 = zd_[1];                                                                                \
    int eg_ = ((tg) << 7) + sr;                                                                  \
    int esg_ = eg_ < E ? eg_ : E - 1;                                                            \
    cv = *(const f32x4*)(ctx + (size_t)esg_ * 32 + sh * 4);                                      \
    int tn_ = (tg) + grid;                                                                       \
    if (tn_ >= nblk) tn_ = (tg);                                                                 \
    int en_ = (tn_ << 7) + sr;                                                                   \
    int esn_ = en_ < E ? en_ : E - 1;                                                            \
    i0n = ei[esn_];                                                                              \
    i1n = ei[E + esn_];                                                                          \
  } while (0)

__global__ __launch_bounds__(1024, 4) void fused_kernel_f(
    const float* __restrict__ z, const int* __restrict__ ei, const float* __restrict__ ctx,
    const unsigned short* __restrict__ w1f, const unsigned short* __restrict__ w2f,
    const float* __restrict__ sc, const float* __restrict__ w3, const float* __restrict__ b3,
    float* __restrict__ out, int E, int nblk) {
  extern __shared__ char lds[];
  char* W1L = lds;
  float* SC = (float*)(lds + F_SC_OFF);
  char* AR = lds + F_A_OFF;
  char* X1 = lds + F_A_OFF;  // alias: x1 overwrites A-head after L1 reads complete
  float* l3 = (float*)(lds + F_L3_OFF);

  const int tid = threadIdx.x;
  const int lane = tid & 63, wave = tid >> 6;
  const int g = lane >> 4, lq = lane & 15;
  const int wr = wave >> 2, wc = wave & 3;   // L1 grid 4x4: 32 rows x 32 cols per wave
  const int w2r = wave >> 1, w2c = wave & 1; // L2 grid 8x2
  const int sr = tid >> 3, sh = tid & 7;     // staging: 8 threads per edge
  const int grid = gridDim.x;

  {
    const f32x4* s = (const f32x4*)w1f;
    f32x4* d = (f32x4*)W1L;
#pragma unroll
    for (int i = 0; i < 4; i++) d[i * 1024 + tid] = s[i * 1024 + tid];
    if (tid < 512) d[4096 + tid] = s[4096 + tid];
    if (tid < 128) {
      SC[tid] = sc[tid];
      SC[128 + tid] = sc[128 + tid];
    } else if (tid < 192) {
      int j = tid - 128;
      SC[256 + j] = sc[256 + j];
      SC[320 + j] = sc[320 + j];
      SC[384 + j] = w3[j];
    } else if (tid == 192) {
      SC[448] = b3[0];
    }
  }

  bf16x8 w2g0, w2g1, w2g2, w2g3, w2h0, w2h1, w2h2, w2h3;
  {
    const bf16x8* W2G = (const bf16x8*)w2f;
    w2g0 = W2G[(0 * 4 + w2c * 2 + 0) * 64 + lane];
    w2h0 = W2G[(0 * 4 + w2c * 2 + 1) * 64 + lane];
    w2g1 = W2G[(1 * 4 + w2c * 2 + 0) * 64 + lane];
    w2h1 = W2G[(1 * 4 + w2c * 2 + 1) * 64 + lane];
    w2g2 = W2G[(2 * 4 + w2c * 2 + 0) * 64 + lane];
    w2h2 = W2G[(2 * 4 + w2c * 2 + 1) * 64 + lane];
    w2g3 = W2G[(3 * 4 + w2c * 2 + 0) * 64 + lane];
    w2h3 = W2G[(3 * 4 + w2c * 2 + 1) * 64 + lane];
  }

  f32x4 sv0, sv1, dv0, dv1, cv;
  int i0n, i1n;
  int t = blockIdx.x;

  {
    int e = (t << 7) + sr;
    int es = e < E ? e : E - 1;
    int a0 = ei[es], a1 = ei[E + es];
    cv = *(const f32x4*)(ctx + (size_t)es * 32 + sh * 4);
    const f32x4* zs = (const f32x4*)(z + ((size_t)a0 * 64 + sh * 8));
    sv0 = zs[0];
    sv1 = zs[1];
    const f32x4* zd = (const f32x4*)(z + ((size_t)a1 * 64 + sh * 8));
    dv0 = zd[0];
    dv1 = zd[1];
    int tn = t + grid;
    if (tn >= nblk) tn = t;
    int en = (tn << 7) + sr;
    int esn = en < E ? en : E - 1;
    i0n = ei[esn];
    i1n = ei[E + esn];
  }
  WRITE_A_F();
  {
    int tn = t + grid;
    if (tn >= nblk) tn = t;
    GATHER_NEXT_F(tn);
  }
  __syncthreads();

  for (; t < nblk; t += grid) {
    f32x4 acc00 = {0.f, 0.f, 0.f, 0.f}, acc01 = acc00, acc10 = acc00, acc11 = acc00;
    const bf16x8* W1F = (const bf16x8*)W1L;
    const int row0 = wr * 32 + lq, row1 = row0 + 16;
    const int swz0 = (row0 & 7) << 4, swz1 = (row1 & 7) << 4;
    const char* ap0 = AR + row0 * 640;
    const char* ap1 = AR + row1 * 640;
#pragma unroll
    for (int kb = 0; kb < 9; kb++) {
      bf16x8 a0 = *(const bf16x8*)(ap0 + ((kb * 64 + g * 16) ^ swz0));
      bf16x8 a1 = *(const bf16x8*)(ap1 + ((kb * 64 + g * 16) ^ swz1));
      bf16x8 b0 = W1F[(kb * 8 + wc * 2 + 0) * 64 + lane];
      bf16x8 b1 = W1F[(kb * 8 + wc * 2 + 1) * 64 + lane];
      acc00 = MFMA16(a0, b0, acc00);
      acc01 = MFMA16(a0, b1, acc01);
      acc10 = MFMA16(a1, b0, acc10);
      acc11 = MFMA16(a1, b1, acc11);
    }
    __syncthreads();

    {
      const int col0 = wc * 32 + lq;
      const float s1v0 = SC[col0], c1v0 = SC[128 + col0];
      const float s1v1 = SC[col0 + 16], c1v1 = SC[128 + col0 + 16];
      const int xoff = wc * 64 + lq * 4;
#pragma unroll
      for (int j = 0; j < 4; j++) {
        int rowa = wr * 32 + 4 * g + j;
        unsigned int pA = cvtpk(fmaxf(acc00[j] * s1v0 + c1v0, 0.f),
                                fmaxf(acc01[j] * s1v1 + c1v1, 0.f));
        *(unsigned int*)(X1 + rowa * 256 + (xoff ^ ((rowa & 7) << 4))) = pA;
        int rowb = rowa + 16;
        unsigned int pB = cvtpk(fmaxf(acc10[j] * s1v0 + c1v0, 0.f),
                                fmaxf(acc11[j] * s1v1 + c1v1, 0.f));
        *(unsigned int*)(X1 + rowb * 256 + (xoff ^ ((rowb & 7) << 4))) = pB;
      }
    }
    __syncthreads();

    f32x4 acc2A = {0.f, 0.f, 0.f, 0.f}, acc2B = acc2A;
    {
      const int row = w2r * 16 + lq;
      const int swz = (row & 7) << 4;
      const char* xp = X1 + row * 256;
      bf16x8 a0 = *(const bf16x8*)(xp + ((0 * 64 + g * 16) ^ swz));
      acc2A = MFMA16(a0, w2g0, acc2A);
      acc2B = MFMA16(a0, w2h0, acc2B);
      bf16x8 a1 = *(const bf16x8*)(xp + ((1 * 64 + g * 16) ^ swz));
      acc2A = MFMA16(a1, w2g1, acc2A);
      acc2B = MFMA16(a1, w2h1, acc2B);
      bf16x8 a2 = *(const bf16x8*)(xp + ((2 * 64 + g * 16) ^ swz));
      acc2A = MFMA16(a2, w2g2, acc2A);
      acc2B = MFMA16(a2, w2h2, acc2B);
      bf16x8 a3 = *(const bf16x8*)(xp + ((3 * 64 + g * 16) ^ swz));
      acc2A = MFMA16(a3, w2g3, acc2A);
      acc2B = MFMA16(a3, w2h3, acc2B);
    }

    const int colA = w2c * 32 + lq, colB = colA + 16;
    const float s2A = SC[256 + colA], c2A = SC[320 + colA];
    const float s2B = SC[256 + colB], c2B = SC[320 + colB];
    const float w3A = SC[384 + colA], w3B = SC[384 + colB];
#pragma unroll
    for (int j = 0; j < 4; j++) {
      float vA = fmaxf(acc2A[j] * s2A + c2A, 0.f);
      float vB = fmaxf(acc2B[j] * s2B + c2B, 0.f);
      float p = vA * w3A + vB * w3B;
      p += __shfl_xor(p, 1);
      p += __shfl_xor(p, 2);
      p += __shfl_xor(p, 4);
      p += __shfl_xor(p, 8);
      if (lq == 0) l3[(w2r * 16 + 4 * g + j) * 2 + w2c] = p;
    }
    __syncthreads();

    WRITE_A_F();
    {
      int tn2 = t + 2 * grid;
      if (tn2 >= nblk) tn2 = t + grid < nblk ? t + grid : t;
      GATHER_NEXT_F(tn2);
    }
    if (tid < 128) {
      int e = (t << 7) + tid;
      if (e < E) out[e] = l3[tid * 2] + l3[tid * 2 + 1] + SC[448];
    }
    __syncthreads();
  }
}

extern "C" void kernel_launch(void* const* d_in, const int* in_sizes, int n_in,
                              void* d_out, int out_size, void* d_ws, size_t ws_size,
                              hipStream_t stream) {
  const float* z = (const float*)d_in[0];
  const int* ei = (const int*)d_in[1];
  const float* ctx = (const float*)d_in[2];
  const float* W1 = (const float*)d_in[3];
  const float* b1 = (const float*)d_in[4];
  const float* g1 = (const float*)d_in[5];
  const float* be1 = (const float*)d_in[6];
  const float* m1 = (const float*)d_in[7];
  const float* v1 = (const float*)d_in[8];
  const float* W2 = (const float*)d_in[9];
  const float* b2 = (const float*)d_in[10];
  const float* g2 = (const float*)d_in[11];
  const float* be2 = (const float*)d_in[12];
  const float* m2 = (const float*)d_in[13];
  const float* v2 = (const float*)d_in[14];
  const float* W3 = (const float*)d_in[15];
  const float* b3 = (const float*)d_in[16];
  float* out = (float*)d_out;
  const int E = out_size;

  unsigned short* w1f = (unsigned short*)d_ws;
  unsigned short* w2f = (unsigned short*)((char*)d_ws + 73728);
  float* sc = (float*)((char*)d_ws + 90112);

  prep_kernel<<<177, 256, 0, stream>>>(W1, W2, b1, g1, be1, m1, v1,
                                       b2, g2, be2, m2, v2, w1f, w2f, sc);

  const int nblk = (E + 127) >> 7;
  (void)hipFuncSetAttribute((const void*)fused_kernel_f,
                            hipFuncAttributeMaxDynamicSharedMemorySize, F_LDS_TOTAL);
  fused_kernel_f<<<256, 1024, F_LDS_TOTAL, stream>>>(z, ei, ctx, w1f, w2f, sc, W3, b3,
                                                     out, E, nblk);
}

// Round 17
// 136.583 us; speedup vs baseline: 1.1853x; 1.0040x over previous
//
#include <hip/hip_runtime.h>
#include <hip/hip_bf16.h>

typedef __attribute__((ext_vector_type(8))) short bf16x8;
typedef __attribute__((ext_vector_type(4))) float f32x4;
typedef __attribute__((ext_vector_type(4))) unsigned int u32x4;
typedef __attribute__((ext_vector_type(2))) unsigned int u32x2;
typedef __attribute__((ext_vector_type(2))) __bf16 bf16x2v;

#define EPS 1e-5f

__device__ inline unsigned short f2bf(float x) {  // RNE (prep kernel only; cold)
  unsigned int u = __builtin_bit_cast(unsigned int, x);
  unsigned int r = (u + 0x7FFFu + ((u >> 16) & 1u)) >> 16;
  return (unsigned short)r;
}

// pair pack: compiles to v_cvt_pk_bf16_f32 (1 VALU op; RNE)
__device__ inline unsigned int cvtpk(float a, float b) {
  bf16x2v v = {(__bf16)a, (__bf16)b};
  return __builtin_bit_cast(unsigned int, v);
}

#define MFMA16(A, B, C) __builtin_amdgcn_mfma_f32_16x16x32_bf16((A), (B), (C), 0, 0, 0)

// derive prod = s(.)d and absd = |s-d| fragments from src/dst fragments, in-register.
// Fragment layout is positional, so elementwise per lane-reg is exact.
__device__ inline void derive_pa(bf16x8 s, bf16x8 d, bf16x8* pr, bf16x8* ad) {
  u32x4 su = __builtin_bit_cast(u32x4, s);
  u32x4 du = __builtin_bit_cast(u32x4, d);
  u32x4 pu, au;
#pragma unroll
  for (int i = 0; i < 4; i++) {
    float slo = __builtin_bit_cast(float, su[i] << 16);
    float shi = __builtin_bit_cast(float, su[i] & 0xFFFF0000u);
    float dlo = __builtin_bit_cast(float, du[i] << 16);
    float dhi = __builtin_bit_cast(float, du[i] & 0xFFFF0000u);
    pu[i] = cvtpk(slo * dlo, shi * dhi);
    au[i] = cvtpk(fabsf(slo - dlo), fabsf(shi - dhi));
  }
  *pr = __builtin_bit_cast(bf16x8, pu);
  *ad = __builtin_bit_cast(bf16x8, au);
}

// ---------------- prep: fold BN, pre-swizzle W1/W2 into MFMA fragment order ----------------
// ws layout: w1f bf16 [73728 B] | w2f bf16 [16384 B] | sc f32[384]
// W2 rows permuted: physical k-slot s holds logical row (s&96)|((s&1)<<4)|((s>>1)&15)
// — matches the packed x1 writes.
__global__ void prep_kernel(const float* __restrict__ W1, const float* __restrict__ W2,
                            const float* __restrict__ b1, const float* __restrict__ g1,
                            const float* __restrict__ be1, const float* __restrict__ m1,
                            const float* __restrict__ v1,
                            const float* __restrict__ b2, const float* __restrict__ g2,
                            const float* __restrict__ be2, const float* __restrict__ m2,
                            const float* __restrict__ v2,
                            unsigned short* __restrict__ w1f, unsigned short* __restrict__ w2f,
                            float* __restrict__ sc) {
  int t = blockIdx.x * 256 + threadIdx.x;
  if (t < 36864) {
    int j = t & 7, l = (t >> 3) & 63, f = t >> 9;
    int kb = f >> 3, nb = f & 7;
    int rk = kb * 32 + ((l >> 4) << 3) + j;
    int cn = (nb << 4) + (l & 15);
    w1f[t] = f2bf(W1[rk * 128 + cn]);
  } else if (t < 45056) {
    int o = t - 36864;
    int j = o & 7, l = (o >> 3) & 63, f = o >> 9;
    int kb = f >> 2, nb = f & 3;
    int s = kb * 32 + ((l >> 4) << 3) + j;                 // physical k-slot
    int rk = (s & 96) | ((s & 1) << 4) | ((s >> 1) & 15);  // logical W2 row
    int cn = (nb << 4) + (l & 15);
    w2f[o] = f2bf(W2[rk * 64 + cn]);
  } else if (t < 45184) {
    int j = t - 45056;
    float s = g1[j] * rsqrtf(v1[j] + EPS);
    sc[j] = s;
    sc[128 + j] = (b1[j] - m1[j]) * s + be1[j];
  } else if (t < 45248) {
    int j = t - 45184;
    float s = g2[j] * rsqrtf(v2[j] + EPS);
    sc[256 + j] = s;
    sc[320 + j] = (b2[j] - m2[j]) * s + be2[j];
  }
}

// ================= PRIMARY v: derived-A kernel (stage only src/dst/ctx; prod/absd in-reg) ===
// A-tile 128 x 384 B (src 128 | dst 128 | ctx 64 + 64 pad). L1 reads 5 frags/row (kb0-3 +
// ctx), derives kb4-7 via derive_pa. LDS/tile 752->~590 KB. Everything else = f structure.
// LDS: [0,73728) W1 | [73728,75776) SC | [75776,124928) A [128x384] (x1 aliases head 32 KB) |
//      [124928,125952) l3
#define V_SC_OFF 73728
#define V_A_OFF 75776
#define V_L3_OFF 124928
#define V_LDS_TOTAL 125952

#define WRITE_A_V()                                                                              \
  do {                                                                                           \
    const int rswz_ = (sr & 7) << 4;                                                             \
    char* rowp_ = AV + sr * 384;                                                                 \
    u32x4 ps_ = {cvtpk(sv0[0], sv0[1]), cvtpk(sv0[2], sv0[3]), cvtpk(sv1[0], sv1[1]),            \
                 cvtpk(sv1[2], sv1[3])};                                                         \
    u32x4 pd_ = {cvtpk(dv0[0], dv0[1]), cvtpk(dv0[2], dv0[3]), cvtpk(dv1[0], dv1[1]),            \
                 cvtpk(dv1[2], dv1[3])};                                                         \
    u32x2 pc_ = {cvtpk(cv[0], cv[1]), cvtpk(cv[2], cv[3])};                                      \
    *(u32x4*)(rowp_ + ((sh * 16) ^ rswz_)) = ps_;                                                \
    *(u32x4*)(rowp_ + ((128 + sh * 16) ^ rswz_)) = pd_;                                          \
    *(u32x2*)(rowp_ + ((256 + sh * 8) ^ rswz_)) = pc_;                                           \
  } while (0)

#define GATHER_NEXT_V(tg)                                                                        \
  do {                                                                                           \
    const f32x4* zs_ = (const f32x4*)(z + ((size_t)i0n * 64 + sh * 8));                          \
    sv0 = zs_[0];                                                                                \
    sv1 = zs_[1];                                                                                \
    const f32x4* zd_ = (const f32x4*)(z + ((size_t)i1n * 64 + sh * 8));                          \
    dv0 = zd_[0];                                                                                \
    dv1 = zd_[1];                                                                                \
    int eg_ = ((tg) << 7) + sr;                                                                  \
    int esg_ = eg_ < E ? eg_ : E - 1;                                                            \
    cv = *(const f32x4*)(ctx + (size_t)esg_ * 32 + sh * 4);                                      \
    int tn_ = (tg) + grid;                                                                       \
    if (tn_ >= nblk) tn_ = (tg);                                                                 \
    int en_ = (tn_ << 7) + sr;                                                                   \
    int esn_ = en_ < E ? en_ : E - 1;                                                            \
    i0n = ei[esn_];                                                                              \
    i1n = ei[E + esn_];                                                                          \
  } while (0)

// one src/dst chunk pair (KS = 0 or 1): MFMAs for kb=KS (src), KS+2 (dst),
// KS+4 (prod, derived), KS+6 (absd, derived)
#define L1PAIR_V(KS)                                                                             \
  do {                                                                                           \
    bf16x8 s0_ = *(const bf16x8*)(ap0 + (((KS) * 64 + g * 16) ^ swz0));                          \
    bf16x8 s1_ = *(const bf16x8*)(ap1 + (((KS) * 64 + g * 16) ^ swz0));                          \
    bf16x8 d0_ = *(const bf16x8*)(ap0 + ((128 + (KS) * 64 + g * 16) ^ swz0));                    \
    bf16x8 d1_ = *(const bf16x8*)(ap1 + ((128 + (KS) * 64 + g * 16) ^ swz0));                    \
    bf16x8 b0_ = W1F[((KS) * 8 + wc * 2 + 0) * 64 + lane];                                       \
    bf16x8 b1_ = W1F[((KS) * 8 + wc * 2 + 1) * 64 + lane];                                       \
    acc00 = MFMA16(s0_, b0_, acc00); acc01 = MFMA16(s0_, b1_, acc01);                            \
    acc10 = MFMA16(s1_, b0_, acc10); acc11 = MFMA16(s1_, b1_, acc11);                            \
    b0_ = W1F[(((KS) + 2) * 8 + wc * 2 + 0) * 64 + lane];                                        \
    b1_ = W1F[(((KS) + 2) * 8 + wc * 2 + 1) * 64 + lane];                                        \
    acc00 = MFMA16(d0_, b0_, acc00); acc01 = MFMA16(d0_, b1_, acc01);                            \
    acc10 = MFMA16(d1_, b0_, acc10); acc11 = MFMA16(d1_, b1_, acc11);                            \
    bf16x8 p0_, a0_, p1_, a1_;                                                                   \
    derive_pa(s0_, d0_, &p0_, &a0_);                                                             \
    derive_pa(s1_, d1_, &p1_, &a1_);                                                             \
    b0_ = W1F[(((KS) + 4) * 8 + wc * 2 + 0) * 64 + lane];                                        \
    b1_ = W1F[(((KS) + 4) * 8 + wc * 2 + 1) * 64 + lane];                                        \
    acc00 = MFMA16(p0_, b0_, acc00); acc01 = MFMA16(p0_, b1_, acc01);                            \
    acc10 = MFMA16(p1_, b0_, acc10); acc11 = MFMA16(p1_, b1_, acc11);                            \
    b0_ = W1F[(((KS) + 6) * 8 + wc * 2 + 0) * 64 + lane];                                        \
    b1_ = W1F[(((KS) + 6) * 8 + wc * 2 + 1) * 64 + lane];                                        \
    acc00 = MFMA16(a0_, b0_, acc00); acc01 = MFMA16(a0_, b1_, acc01);                            \
    acc10 = MFMA16(a1_, b0_, acc10); acc11 = MFMA16(a1_, b1_, acc11);                            \
  } while (0)

__global__ __launch_bounds__(1024) void fused_kernel_v(
    const float* __restrict__ z, const int* __restrict__ ei, const float* __restrict__ ctx,
    const unsigned short* __restrict__ w1f, const unsigned short* __restrict__ w2f,
    const float* __restrict__ sc, const float* __restrict__ w3, const float* __restrict__ b3,
    float* __restrict__ out, int E, int nblk) {
  extern __shared__ char lds[];
  char* W1L = lds;
  float* SC = (float*)(lds + V_SC_OFF);
  char* AV = lds + V_A_OFF;
  char* X1 = lds + V_A_OFF;  // alias: x1 overwrites A-head after L1 reads complete
  float* l3 = (float*)(lds + V_L3_OFF);

  const int tid = threadIdx.x;
  const int lane = tid & 63, wave = tid >> 6;
  const int g = lane >> 4, lq = lane & 15;
  const int wr = wave >> 2, wc = wave & 3;   // L1 grid 4x4: 32 rows x 32 cols per wave
  const int w2r = wave >> 1, w2c = wave & 1; // L2 grid 8x2
  const int sr = tid >> 3, sh = tid & 7;     // staging: 8 threads per edge
  const int grid = gridDim.x;

  {
    const f32x4* s = (const f32x4*)w1f;
    f32x4* d = (f32x4*)W1L;
#pragma unroll
    for (int i = 0; i < 4; i++) d[i * 1024 + tid] = s[i * 1024 + tid];
    if (tid < 512) d[4096 + tid] = s[4096 + tid];
    if (tid < 128) {
      SC[tid] = sc[tid];
      SC[128 + tid] = sc[128 + tid];
    } else if (tid < 192) {
      int j = tid - 128;
      SC[256 + j] = sc[256 + j];
      SC[320 + j] = sc[320 + j];
      SC[384 + j] = w3[j];
    } else if (tid == 192) {
      SC[448] = b3[0];
    }
  }

  bf16x8 w2g0, w2g1, w2g2, w2g3, w2h0, w2h1, w2h2, w2h3;
  {
    const bf16x8* W2G = (const bf16x8*)w2f;
    w2g0 = W2G[(0 * 4 + w2c * 2 + 0) * 64 + lane];
    w2h0 = W2G[(0 * 4 + w2c * 2 + 1) * 64 + lane];
    w2g1 = W2G[(1 * 4 + w2c * 2 + 0) * 64 + lane];
    w2h1 = W2G[(1 * 4 + w2c * 2 + 1) * 64 + lane];
    w2g2 = W2G[(2 * 4 + w2c * 2 + 0) * 64 + lane];
    w2h2 = W2G[(2 * 4 + w2c * 2 + 1) * 64 + lane];
    w2g3 = W2G[(3 * 4 + w2c * 2 + 0) * 64 + lane];
    w2h3 = W2G[(3 * 4 + w2c * 2 + 1) * 64 + lane];
  }

  f32x4 sv0, sv1, dv0, dv1, cv;
  int i0n, i1n;
  int t = blockIdx.x;

  {
    int e = (t << 7) + sr;
    int es = e < E ? e : E - 1;
    int a0 = ei[es], a1 = ei[E + es];
    cv = *(const f32x4*)(ctx + (size_t)es * 32 + sh * 4);
    const f32x4* zs = (const f32x4*)(z + ((size_t)a0 * 64 + sh * 8));
    sv0 = zs[0];
    sv1 = zs[1];
    const f32x4* zd = (const f32x4*)(z + ((size_t)a1 * 64 + sh * 8));
    dv0 = zd[0];
    dv1 = zd[1];
    int tn = t + grid;
    if (tn >= nblk) tn = t;
    int en = (tn << 7) + sr;
    int esn = en < E ? en : E - 1;
    i0n = ei[esn];
    i1n = ei[E + esn];
  }
  WRITE_A_V();
  {
    int tn = t + grid;
    if (tn >= nblk) tn = t;
    GATHER_NEXT_V(tn);
  }
  __syncthreads();

  const bf16x8* W1F = (const bf16x8*)W1L;
  for (; t < nblk; t += grid) {
    // ---- layer 1: 5 A-frag reads/row, kb4-7 derived in-register ----
    f32x4 acc00 = {0.f, 0.f, 0.f, 0.f}, acc01 = acc00, acc10 = acc00, acc11 = acc00;
    const int row0 = wr * 32 + lq;
    const int swz0 = (row0 & 7) << 4;  // row1=row0+16 has same &7
    const char* ap0 = AV + row0 * 384;
    const char* ap1 = ap0 + 16 * 384;
    L1PAIR_V(0);
    L1PAIR_V(1);
    {
      bf16x8 c0 = *(const bf16x8*)(ap0 + ((256 + g * 16) ^ swz0));
      bf16x8 c1 = *(const bf16x8*)(ap1 + ((256 + g * 16) ^ swz0));
      bf16x8 b0 = W1F[(8 * 8 + wc * 2 + 0) * 64 + lane];
      bf16x8 b1 = W1F[(8 * 8 + wc * 2 + 1) * 64 + lane];
      acc00 = MFMA16(c0, b0, acc00);
      acc01 = MFMA16(c0, b1, acc01);
      acc10 = MFMA16(c1, b0, acc10);
      acc11 = MFMA16(c1, b1, acc11);
    }
    __syncthreads();  // all A(t) reads done; X1 alias region writable

    // ---- x1-write(t): bn+relu, packed u32 pairs at permuted slots ----
    {
      const int col0 = wc * 32 + lq;
      const float s1v0 = SC[col0], c1v0 = SC[128 + col0];
      const float s1v1 = SC[col0 + 16], c1v1 = SC[128 + col0 + 16];
      const int xoff = wc * 64 + lq * 4;
#pragma unroll
      for (int j = 0; j < 4; j++) {
        int rowa = wr * 32 + 4 * g + j;
        unsigned int pA = cvtpk(fmaxf(acc00[j] * s1v0 + c1v0, 0.f),
                                fmaxf(acc01[j] * s1v1 + c1v1, 0.f));
        *(unsigned int*)(X1 + rowa * 256 + (xoff ^ ((rowa & 7) << 4))) = pA;
        int rowb = rowa + 16;
        unsigned int pB = cvtpk(fmaxf(acc10[j] * s1v0 + c1v0, 0.f),
                                fmaxf(acc11[j] * s1v1 + c1v1, 0.f));
        *(unsigned int*)(X1 + rowb * 256 + (xoff ^ ((rowb & 7) << 4))) = pB;
      }
    }
    __syncthreads();  // x1(t) visible

    // ---- layer 2: x1[128x128] @ W2[128x64]; W2 from regs ----
    f32x4 acc2A = {0.f, 0.f, 0.f, 0.f}, acc2B = acc2A;
    {
      const int row = w2r * 16 + lq;
      const int swz = (row & 7) << 4;
      const char* xp = X1 + row * 256;
      bf16x8 a0 = *(const bf16x8*)(xp + ((0 * 64 + g * 16) ^ swz));
      acc2A = MFMA16(a0, w2g0, acc2A);
      acc2B = MFMA16(a0, w2h0, acc2B);
      bf16x8 a1 = *(const bf16x8*)(xp + ((1 * 64 + g * 16) ^ swz));
      acc2A = MFMA16(a1, w2g1, acc2A);
      acc2B = MFMA16(a1, w2h1, acc2B);
      bf16x8 a2 = *(const bf16x8*)(xp + ((2 * 64 + g * 16) ^ swz));
      acc2A = MFMA16(a2, w2g2, acc2A);
      acc2B = MFMA16(a2, w2h2, acc2B);
      bf16x8 a3 = *(const bf16x8*)(xp + ((3 * 64 + g * 16) ^ swz));
      acc2A = MFMA16(a3, w2g3, acc2A);
      acc2B = MFMA16(a3, w2h3, acc2B);
    }

    // ---- layer 3: bn+relu, dot w3, 16-lane shfl reduce ----
    const int colA = w2c * 32 + lq, colB = colA + 16;
    const float s2A = SC[256 + colA], c2A = SC[320 + colA];
    const float s2B = SC[256 + colB], c2B = SC[320 + colB];
    const float w3A = SC[384 + colA], w3B = SC[384 + colB];
#pragma unroll
    for (int j = 0; j < 4; j++) {
      float vA = fmaxf(acc2A[j] * s2A + c2A, 0.f);
      float vB = fmaxf(acc2B[j] * s2B + c2B, 0.f);
      float p = vA * w3A + vB * w3B;
      p += __shfl_xor(p, 1);
      p += __shfl_xor(p, 2);
      p += __shfl_xor(p, 4);
      p += __shfl_xor(p, 8);
      if (lq == 0) l3[(w2r * 16 + 4 * g + j) * 2 + w2c] = p;
    }
    __syncthreads();  // l3 visible; x1 reads done -> A region writable

    // ---- phase 4: A-write(t+1) | issue gathers(t+2) | out(t) ----
    WRITE_A_V();
    {
      int tn2 = t + 2 * grid;
      if (tn2 >= nblk) tn2 = t + grid < nblk ? t + grid : t;
      GATHER_NEXT_V(tn2);
    }
    if (tid < 128) {
      int e = (t << 7) + tid;
      if (e < E) out[e] = l3[tid * 2] + l3[tid * 2 + 1] + SC[448];
    }
    __syncthreads();  // A(t+1) visible
  }
}

// ================= FALLBACK f: proven 137-us kernel =================
#define F_SC_OFF 73728
#define F_A_OFF 75776
#define F_L3_OFF 157696
#define F_LDS_TOTAL 158720

#define WRITE_A_F()                                                                              \
  do {                                                                                           \
    const int rswz_ = (sr & 7) << 4;                                                             \
    char* rowp_ = AR + sr * 640;                                                                 \
    u32x4 ps_ = {cvtpk(sv0[0], sv0[1]), cvtpk(sv0[2], sv0[3]), cvtpk(sv1[0], sv1[1]),            \
                 cvtpk(sv1[2], sv1[3])};                                                         \
    u32x4 pd_ = {cvtpk(dv0[0], dv0[1]), cvtpk(dv0[2], dv0[3]), cvtpk(dv1[0], dv1[1]),            \
                 cvtpk(dv1[2], dv1[3])};                                                         \
    u32x4 pp_ = {cvtpk(sv0[0] * dv0[0], sv0[1] * dv0[1]), cvtpk(sv0[2] * dv0[2], sv0[3] * dv0[3]),\
                 cvtpk(sv1[0] * dv1[0], sv1[1] * dv1[1]), cvtpk(sv1[2] * dv1[2], sv1[3] * dv1[3])};\
    u32x4 pa_ = {cvtpk(fabsf(sv0[0] - dv0[0]), fabsf(sv0[1] - dv0[1])),                          \
                 cvtpk(fabsf(sv0[2] - dv0[2]), fabsf(sv0[3] - dv0[3])),                          \
                 cvtpk(fabsf(sv1[0] - dv1[0]), fabsf(sv1[1] - dv1[1])),                          \
                 cvtpk(fabsf(sv1[2] - dv1[2]), fabsf(sv1[3] - dv1[3]))};                         \
    u32x2 pc_ = {cvtpk(cv[0], cv[1]), cvtpk(cv[2], cv[3])};                                      \
    *(u32x4*)(rowp_ + ((sh * 16) ^ rswz_)) = ps_;                                                \
    *(u32x4*)(rowp_ + ((128 + sh * 16) ^ rswz_)) = pd_;                                          \
    *(u32x4*)(rowp_ + ((256 + sh * 16) ^ rswz_)) = pp_;                                          \
    *(u32x4*)(rowp_ + ((384 + sh * 16) ^ rswz_)) = pa_;                                          \
    *(u32x2*)(rowp_ + 512 + ((sh * 8) ^ rswz_)) = pc_;                                           \
  } while (0)

#define GATHER_NEXT_F(tg)                                                                        \
  do {                                                                                           \
    const f32x4* zs_ = (const f32x4*)(z + ((size_t)i0n * 64 + sh * 8));                          \
    sv0 = zs_[0];                                                                                \
    sv1 = zs_[1];                                                                                \
    const f32x4* zd_ = (const f32x4*)(z + ((size_t)i1n * 64 + sh * 8));                          \
    dv0 = zd_[0];                                                                                \
    dv1 = zd_[1];                                                                                \
    int eg_ = ((tg) << 7) + sr;                                                                  \
    int esg_ = eg_ < E ? eg_ : E - 1;                                                            \
    cv = *(const f32x4*)(ctx + (size_t)esg_ * 32 + sh * 4);                                      \
    int tn_ = (tg) + grid;                                                                       \
    if (tn_ >= nblk) tn_ = (tg);                                                                 \
    int en_ = (tn_ << 7) + sr;                                                                   \
    int esn_ = en_ < E ? en_ : E - 1;                                                            \
    i0n = ei[esn_];                                                                              \
    i1n = ei[E + esn_];                                                                          \
  } while (0)

__global__ __launch_bounds__(1024, 4) void fused_kernel_f(
    const float* __restrict__ z, const int* __restrict__ ei, const float* __restrict__ ctx,
    const unsigned short* __restrict__ w1f, const unsigned short* __restrict__ w2f,
    const float* __restrict__ sc, const float* __restrict__ w3, const float* __restrict__ b3,
    float* __restrict__ out, int E, int nblk) {
  extern __shared__ char lds[];
  char* W1L = lds;
  float* SC = (float*)(lds + F_SC_OFF);
  char* AR = lds + F_A_OFF;
  char* X1 = lds + F_A_OFF;
  float* l3 = (float*)(lds + F_L3_OFF);

  const int tid = threadIdx.x;
  const int lane = tid & 63, wave = tid >> 6;
  const int g = lane >> 4, lq = lane & 15;
  const int wr = wave >> 2, wc = wave & 3;
  const int w2r = wave >> 1, w2c = wave & 1;
  const int sr = tid >> 3, sh = tid & 7;
  const int grid = gridDim.x;

  {
    const f32x4* s = (const f32x4*)w1f;
    f32x4* d = (f32x4*)W1L;
#pragma unroll
    for (int i = 0; i < 4; i++) d[i * 1024 + tid] = s[i * 1024 + tid];
    if (tid < 512) d[4096 + tid] = s[4096 + tid];
    if (tid < 128) {
      SC[tid] = sc[tid];
      SC[128 + tid] = sc[128 + tid];
    } else if (tid < 192) {
      int j = tid - 128;
      SC[256 + j] = sc[256 + j];
      SC[320 + j] = sc[320 + j];
      SC[384 + j] = w3[j];
    } else if (tid == 192) {
      SC[448] = b3[0];
    }
  }

  bf16x8 w2g0, w2g1, w2g2, w2g3, w2h0, w2h1, w2h2, w2h3;
  {
    const bf16x8* W2G = (const bf16x8*)w2f;
    w2g0 = W2G[(0 * 4 + w2c * 2 + 0) * 64 + lane];
    w2h0 = W2G[(0 * 4 + w2c * 2 + 1) * 64 + lane];
    w2g1 = W2G[(1 * 4 + w2c * 2 + 0) * 64 + lane];
    w2h1 = W2G[(1 * 4 + w2c * 2 + 1) * 64 + lane];
    w2g2 = W2G[(2 * 4 + w2c * 2 + 0) * 64 + lane];
    w2h2 = W2G[(2 * 4 + w2c * 2 + 1) * 64 + lane];
    w2g3 = W2G[(3 * 4 + w2c * 2 + 0) * 64 + lane];
    w2h3 = W2G[(3 * 4 + w2c * 2 + 1) * 64 + lane];
  }

  f32x4 sv0, sv1, dv0, dv1, cv;
  int i0n, i1n;
  int t = blockIdx.x;

  {
    int e = (t << 7) + sr;
    int es = e < E ? e : E - 1;
    int a0 = ei[es], a1 = ei[E + es];
    cv = *(const f32x4*)(ctx + (size_t)es * 32 + sh * 4);
    const f32x4* zs = (const f32x4*)(z + ((size_t)a0 * 64 + sh * 8));
    sv0 = zs[0];
    sv1 = zs[1];
    const f32x4* zd = (const f32x4*)(z + ((size_t)a1 * 64 + sh * 8));
    dv0 = zd[0];
    dv1 = zd[1];
    int tn = t + grid;
    if (tn >= nblk) tn = t;
    int en = (tn << 7) + sr;
    int esn = en < E ? en : E - 1;
    i0n = ei[esn];
    i1n = ei[E + esn];
  }
  WRITE_A_F();
  {
    int tn = t + grid;
    if (tn >= nblk) tn = t;
    GATHER_NEXT_F(tn);
  }
  __syncthreads();

  for (; t < nblk; t += grid) {
    f32x4 acc00 = {0.f, 0.f, 0.f, 0.f}, acc01 = acc00, acc10 = acc00, acc11 = acc00;
    const bf16x8* W1F = (const bf16x8*)W1L;
    const int row0 = wr * 32 + lq, row1 = row0 + 16;
    const int swz0 = (row0 & 7) << 4, swz1 = (row1 & 7) << 4;
    const char* ap0 = AR + row0 * 640;
    const char* ap1 = AR + row1 * 640;
#pragma unroll
    for (int kb = 0; kb < 9; kb++) {
      bf16x8 a0 = *(const bf16x8*)(ap0 + ((kb * 64 + g * 16) ^ swz0));
      bf16x8 a1 = *(const bf16x8*)(ap1 + ((kb * 64 + g * 16) ^ swz1));
      bf16x8 b0 = W1F[(kb * 8 + wc * 2 + 0) * 64 + lane];
      bf16x8 b1 = W1F[(kb * 8 + wc * 2 + 1) * 64 + lane];
      acc00 = MFMA16(a0, b0, acc00);
      acc01 = MFMA16(a0, b1, acc01);
      acc10 = MFMA16(a1, b0, acc10);
      acc11 = MFMA16(a1, b1, acc11);
    }
    __syncthreads();

    {
      const int col0 = wc * 32 + lq;
      const float s1v0 = SC[col0], c1v0 = SC[128 + col0];
      const float s1v1 = SC[col0 + 16], c1v1 = SC[128 + col0 + 16];
      const int xoff = wc * 64 + lq * 4;
#pragma unroll
      for (int j = 0; j < 4; j++) {
        int rowa = wr * 32 + 4 * g + j;
        unsigned int pA = cvtpk(fmaxf(acc00[j] * s1v0 + c1v0, 0.f),
                                fmaxf(acc01[j] * s1v1 + c1v1, 0.f));
        *(unsigned int*)(X1 + rowa * 256 + (xoff ^ ((rowa & 7) << 4))) = pA;
        int rowb = rowa + 16;
        unsigned int pB = cvtpk(fmaxf(acc10[j] * s1v0 + c1v0, 0.f),
                                fmaxf(acc11[j] * s1v1 + c1v1, 0.f));
        *(unsigned int*)(X1 + rowb * 256 + (xoff ^ ((rowb & 7) << 4))) = pB;
      }
    }
    __syncthreads();

    f32x4 acc2A = {0.f, 0.f, 0.f, 0.f}, acc2B = acc2A;
    {
      const int row = w2r * 16 + lq;
      const int swz = (row & 7) << 4;
      const char* xp = X1 + row * 256;
      bf16x8 a0 = *(const bf16x8*)(xp + ((0 * 64 + g * 16) ^ swz));
      acc2A = MFMA16(a0, w2g0, acc2A);
      acc2B = MFMA16(a0, w2h0, acc2B);
      bf16x8 a1 = *(const bf16x8*)(xp + ((1 * 64 + g * 16) ^ swz));
      acc2A = MFMA16(a1, w2g1, acc2A);
      acc2B = MFMA16(a1, w2h1, acc2B);
      bf16x8 a2 = *(const bf16x8*)(xp + ((2 * 64 + g * 16) ^ swz));
      acc2A = MFMA16(a2, w2g2, acc2A);
      acc2B = MFMA16(a2, w2h2, acc2B);
      bf16x8 a3 = *(const bf16x8*)(xp + ((3 * 64 + g * 16) ^ swz));
      acc2A = MFMA16(a3, w2g3, acc2A);
      acc2B = MFMA16(a3, w2h3, acc2B);
    }

    const int colA = w2c * 32 + lq, colB = colA + 16;
    const float s2A = SC[256 + colA], c2A = SC[320 + colA];
    const float s2B = SC[256 + colB], c2B = SC[320 + colB];
    const float w3A = SC[384 + colA], w3B = SC[384 + colB];
#pragma unroll
    for (int j = 0; j < 4; j++) {
      float vA = fmaxf(acc2A[j] * s2A + c2A, 0.f);
      float vB = fmaxf(acc2B[j] * s2B + c2B, 0.f);
      float p = vA * w3A + vB * w3B;
      p += __shfl_xor(p, 1);
      p += __shfl_xor(p, 2);
      p += __shfl_xor(p, 4);
      p += __shfl_xor(p, 8);
      if (lq == 0) l3[(w2r * 16 + 4 * g + j) * 2 + w2c] = p;
    }
    __syncthreads();

    WRITE_A_F();
    {
      int tn2 = t + 2 * grid;
      if (tn2 >= nblk) tn2 = t + grid < nblk ? t + grid : t;
      GATHER_NEXT_F(tn2);
    }
    if (tid < 128) {
      int e = (t << 7) + tid;
      if (e < E) out[e] = l3[tid * 2] + l3[tid * 2 + 1] + SC[448];
    }
    __syncthreads();
  }
}

extern "C" void kernel_launch(void* const* d_in, const int* in_sizes, int n_in,
                              void* d_out, int out_size, void* d_ws, size_t ws_size,
                              hipStream_t stream) {
  const float* z = (const float*)d_in[0];
  const int* ei = (const int*)d_in[1];
  const float* ctx = (const float*)d_in[2];
  const float* W1 = (const float*)d_in[3];
  const float* b1 = (const float*)d_in[4];
  const float* g1 = (const float*)d_in[5];
  const float* be1 = (const float*)d_in[6];
  const float* m1 = (const float*)d_in[7];
  const float* v1 = (const float*)d_in[8];
  const float* W2 = (const float*)d_in[9];
  const float* b2 = (const float*)d_in[10];
  const float* g2 = (const float*)d_in[11];
  const float* be2 = (const float*)d_in[12];
  const float* m2 = (const float*)d_in[13];
  const float* v2 = (const float*)d_in[14];
  const float* W3 = (const float*)d_in[15];
  const float* b3 = (const float*)d_in[16];
  float* out = (float*)d_out;
  const int E = out_size;

  unsigned short* w1f = (unsigned short*)d_ws;
  unsigned short* w2f = (unsigned short*)((char*)d_ws + 73728);
  float* sc = (float*)((char*)d_ws + 90112);

  prep_kernel<<<177, 256, 0, stream>>>(W1, W2, b1, g1, be1, m1, v1,
                                       b2, g2, be2, m2, v2, w1f, w2f, sc);

  const int nblk = (E + 127) >> 7;

  // Primary (derived-A) only if spill-free; else proven 137-us fallback.
  hipFuncAttributes attr;
  bool use_v = false;
  if (hipFuncGetAttributes(&attr, (const void*)fused_kernel_v) == hipSuccess) {
    use_v = (attr.localSizeBytes < 16);
  }

  if (use_v) {
    (void)hipFuncSetAttribute((const void*)fused_kernel_v,
                              hipFuncAttributeMaxDynamicSharedMemorySize, V_LDS_TOTAL);
    fused_kernel_v<<<256, 1024, V_LDS_TOTAL, stream>>>(z, ei, ctx, w1f, w2f, sc, W3, b3,
                                                       out, E, nblk);
  } else {
    (void)hipFuncSetAttribute((const void*)fused_kernel_f,
                              hipFuncAttributeMaxDynamicSharedMemorySize, F_LDS_TOTAL);
    fused_kernel_f<<<256, 1024, F_LDS_TOTAL, stream>>>(z, ei, ctx, w1f, w2f, sc, W3, b3,
                                                       out, E, nblk);
  }
}